// Round 1
// baseline (432.785 us; speedup 1.0000x reference)
//
#include <hip/hip_runtime.h>
#include <hip/hip_bf16.h>
#include <stdint.h>

#define B_N 4096
#define T_N 8
#define DIN 4096
#define H2C 512
#define HC 256

typedef __attribute__((ext_vector_type(8))) short bf16x8;
typedef __attribute__((ext_vector_type(4))) float f32x4;

static __device__ __forceinline__ unsigned short f2bf(float f) {
    union { float f; uint32_t u; } v; v.f = f;
    uint32_t u = v.u;
    uint32_t r = (u + 0x7FFFu + ((u >> 16) & 1u)) >> 16;
    return (unsigned short)r;
}

// ---------------- bucketing ----------------
__global__ void k_hist(const int* __restrict__ task_ids, int* __restrict__ counts) {
    int i = blockIdx.x * blockDim.x + threadIdx.x;
    if (i < B_N) atomicAdd(&counts[task_ids[i]], 1);
}

__global__ void k_scan(const int* __restrict__ counts, int* __restrict__ seg, int* __restrict__ cursor) {
    if (threadIdx.x == 0) {
        int s = 0;
        for (int t = 0; t < T_N; ++t) { seg[t] = s; cursor[t] = s; s += counts[t]; }
    }
}

__global__ void k_scatter(const int* __restrict__ task_ids, int* __restrict__ cursor,
                          int* __restrict__ order, int* __restrict__ tpos) {
    int i = blockIdx.x * blockDim.x + threadIdx.x;
    if (i < B_N) {
        int t = task_ids[i];
        int p = atomicAdd(&cursor[t], 1);
        order[p] = i;
        tpos[p] = t;
    }
}

// ---------------- X concat + fp32->bf16 ----------------
__global__ void k_convert_x(const float* __restrict__ f0, const float* __restrict__ f1,
                            const float* __restrict__ f2, const float* __restrict__ f3,
                            unsigned short* __restrict__ X) {
    int g = blockIdx.x * 256 + threadIdx.x;      // 2,097,152 granules of 8 elems
    size_t e = (size_t)g * 8;
    int b = g >> 9;
    int col = (int)(e & 4095);
    int m = col >> 10, d = col & 1023;
    const float* s = (m == 0) ? f0 : (m == 1) ? f1 : (m == 2) ? f2 : f3;
    const float4* sp = (const float4*)(s + (size_t)b * 1024 + d);
    float4 a = sp[0], c = sp[1];
    uint4 w;
    w.x = (uint32_t)f2bf(a.x) | ((uint32_t)f2bf(a.y) << 16);
    w.y = (uint32_t)f2bf(a.z) | ((uint32_t)f2bf(a.w) << 16);
    w.z = (uint32_t)f2bf(c.x) | ((uint32_t)f2bf(c.y) << 16);
    w.w = (uint32_t)f2bf(c.z) | ((uint32_t)f2bf(c.w) << 16);
    *(uint4*)(X + e) = w;
}

// ---------------- weight transpose [T][R][C] fp32 -> [T][C][R] bf16 ----------------
__global__ void k_transpose_bf(const float* __restrict__ in, unsigned short* __restrict__ out,
                               int R, int C) {
    __shared__ float tile[32][33];
    int t = blockIdx.z;
    const float* ip = in + (size_t)t * R * C;
    unsigned short* op = out + (size_t)t * R * C;
    int r0 = blockIdx.x * 32, c0 = blockIdx.y * 32;
    int c = threadIdx.x & 31, r = threadIdx.x >> 5;
    for (int i = 0; i < 4; ++i) {
        int rr = r + i * 8;
        tile[rr][c] = ip[(size_t)(r0 + rr) * C + c0 + c];
    }
    __syncthreads();
    for (int i = 0; i < 4; ++i) {
        int rr = r + i * 8;
        op[(size_t)(c0 + rr) * R + r0 + c] = f2bf(tile[c][rr]);
    }
}

// ---------------- per-task bias: bw + task_emb @ Ww[256:512] ----------------
__global__ void k_taskbias(const float* __restrict__ temb, const float* __restrict__ Ww,
                           const float* __restrict__ bw, float* __restrict__ tb) {
    int i = threadIdx.x;
    if (i < 32) {
        int t = i >> 2, m = i & 3;
        float s = bw[t * 4 + m];
        const float* te = temb + t * HC;
        const float* w = Ww + (size_t)t * H2C * 4 + HC * 4 + m;
        for (int h = 0; h < HC; ++h) s += te[h] * w[h * 4];
        tb[i] = s;
    }
}

// ---------------- grouped GEMM: rows of task t (sorted), Bt is [T][N][K] bf16 ----------------
__launch_bounds__(256)
__global__ void k_gemm(const unsigned short* __restrict__ A, const unsigned short* __restrict__ Bt,
                       float* __restrict__ C, const int* __restrict__ order,
                       const int* __restrict__ seg, const int* __restrict__ counts,
                       int K, int rowtiles, int coltiles, int Ntot) {
    int t = blockIdx.x / (rowtiles * coltiles);
    int rem = blockIdx.x % (rowtiles * coltiles);
    int rt = rem / coltiles, ct = rem % coltiles;
    int cnt = counts[t];
    if (rt * 128 >= cnt) return;
    int seg0 = seg[t];

    __shared__ unsigned short As[128 * 64];
    __shared__ unsigned short Bs[128 * 64];

    int tid = threadIdx.x, lane = tid & 63, wid = tid >> 6;
    int wm = wid >> 1, wn = wid & 1;

    const unsigned short* srcA[4];
    const unsigned short* srcB[4];
    int sOff[4];
    const unsigned short* BtT = Bt + (size_t)t * Ntot * K;
    for (int i = 0; i < 4; ++i) {
        int g = i * 256 + tid;
        int row = g >> 3, c8 = g & 7;
        int pt = rt * 128 + row;
        if (pt >= cnt) pt = 0;
        int ar = order ? order[seg0 + pt] : (seg0 + pt);
        srcA[i] = A + (size_t)ar * K + c8 * 8;
        srcB[i] = BtT + (size_t)(ct * 128 + row) * K + c8 * 8;
        sOff[i] = row * 64 + ((c8 ^ (row & 7)) * 8);
    }

    f32x4 acc[4][4];
    for (int m = 0; m < 4; ++m)
        for (int n = 0; n < 4; ++n)
            acc[m][n] = (f32x4){0.f, 0.f, 0.f, 0.f};

    for (int k0 = 0; k0 < K; k0 += 64) {
        int4 va[4], vb[4];
        for (int i = 0; i < 4; ++i) va[i] = *(const int4*)(srcA[i] + k0);
        for (int i = 0; i < 4; ++i) vb[i] = *(const int4*)(srcB[i] + k0);
        __syncthreads();
        for (int i = 0; i < 4; ++i) {
            *(int4*)&As[sOff[i]] = va[i];
            *(int4*)&Bs[sOff[i]] = vb[i];
        }
        __syncthreads();
        for (int ks = 0; ks < 2; ++ks) {
            int idx = ks * 4 + (lane >> 4);
            bf16x8 af[4], bfr[4];
            for (int m = 0; m < 4; ++m) {
                int row = wm * 64 + m * 16 + (lane & 15);
                af[m] = *(const bf16x8*)&As[row * 64 + ((idx ^ (row & 7)) * 8)];
            }
            for (int n = 0; n < 4; ++n) {
                int row = wn * 64 + n * 16 + (lane & 15);
                bfr[n] = *(const bf16x8*)&Bs[row * 64 + ((idx ^ (row & 7)) * 8)];
            }
            for (int m = 0; m < 4; ++m)
                for (int n = 0; n < 4; ++n)
                    acc[m][n] = __builtin_amdgcn_mfma_f32_16x16x32_bf16(af[m], bfr[n], acc[m][n], 0, 0, 0);
        }
    }

    for (int m = 0; m < 4; ++m) {
        for (int n = 0; n < 4; ++n) {
            int col = ct * 128 + wn * 64 + n * 16 + (lane & 15);
            for (int j = 0; j < 4; ++j) {
                int row = wm * 64 + m * 16 + (lane >> 4) * 4 + j;
                int pt = rt * 128 + row;
                if (pt < cnt)
                    C[(size_t)(seg0 + pt) * Ntot + col] = acc[m][n][j];
            }
        }
    }
}

// ---------------- LN1 + ReLU + bf16 (rows sorted) ----------------
__global__ void k_ln1(const float* __restrict__ h1raw, const float* __restrict__ b1,
                      const float* __restrict__ g1, const float* __restrict__ be1,
                      const int* __restrict__ tpos, unsigned short* __restrict__ h1b) {
    int p = blockIdx.x * 4 + (threadIdx.x >> 6);
    int lane = threadIdx.x & 63;
    int t = tpos[p];
    const float* r = h1raw + (size_t)p * H2C + lane * 8;
    const float* bb = b1 + t * H2C + lane * 8;
    float4 v0 = *(const float4*)r, v1 = *(const float4*)(r + 4);
    float4 q0 = *(const float4*)bb, q1 = *(const float4*)(bb + 4);
    float x[8] = {v0.x + q0.x, v0.y + q0.y, v0.z + q0.z, v0.w + q0.w,
                  v1.x + q1.x, v1.y + q1.y, v1.z + q1.z, v1.w + q1.w};
    float s = 0.f, sq = 0.f;
    for (int i = 0; i < 8; ++i) { s += x[i]; sq += x[i] * x[i]; }
    for (int o = 32; o > 0; o >>= 1) { s += __shfl_xor(s, o); sq += __shfl_xor(sq, o); }
    float mean = s * (1.0f / H2C);
    float var = sq * (1.0f / H2C) - mean * mean;
    float rstd = rsqrtf(var + 1e-5f);
    const float* gg = g1 + t * H2C + lane * 8;
    const float* ee = be1 + t * H2C + lane * 8;
    float4 g0 = *(const float4*)gg, g1v = *(const float4*)(gg + 4);
    float4 e0 = *(const float4*)ee, e1v = *(const float4*)(ee + 4);
    float gA[8] = {g0.x, g0.y, g0.z, g0.w, g1v.x, g1v.y, g1v.z, g1v.w};
    float eA[8] = {e0.x, e0.y, e0.z, e0.w, e1v.x, e1v.y, e1v.z, e1v.w};
    unsigned short y[8];
    for (int i = 0; i < 8; ++i)
        y[i] = f2bf(fmaxf((x[i] - mean) * rstd * gA[i] + eA[i], 0.f));
    uint4 w;
    w.x = (uint32_t)y[0] | ((uint32_t)y[1] << 16);
    w.y = (uint32_t)y[2] | ((uint32_t)y[3] << 16);
    w.z = (uint32_t)y[4] | ((uint32_t)y[5] << 16);
    w.w = (uint32_t)y[6] | ((uint32_t)y[7] << 16);
    *(uint4*)(h1b + (size_t)p * H2C + lane * 8) = w;
}

// ---------------- LN2 + ReLU + weight-net dot + softmax + scatter ----------------
__global__ void k_ln2_final(const float* __restrict__ h2raw, const float* __restrict__ b2,
                            const float* __restrict__ g2, const float* __restrict__ be2,
                            const float* __restrict__ Ww, const float* __restrict__ tb,
                            const int* __restrict__ tpos, const int* __restrict__ order,
                            float* __restrict__ out) {
    int p = blockIdx.x * 4 + (threadIdx.x >> 6);
    int lane = threadIdx.x & 63;
    int t = tpos[p];
    float4 x4 = *(const float4*)(h2raw + (size_t)p * HC + lane * 4);
    float4 b4 = *(const float4*)(b2 + t * HC + lane * 4);
    float x[4] = {x4.x + b4.x, x4.y + b4.y, x4.z + b4.z, x4.w + b4.w};
    float s = 0.f, sq = 0.f;
    for (int i = 0; i < 4; ++i) { s += x[i]; sq += x[i] * x[i]; }
    for (int o = 32; o > 0; o >>= 1) { s += __shfl_xor(s, o); sq += __shfl_xor(sq, o); }
    float mean = s * (1.0f / HC);
    float var = sq * (1.0f / HC) - mean * mean;
    float rstd = rsqrtf(var + 1e-5f);
    float4 g4 = *(const float4*)(g2 + t * HC + lane * 4);
    float4 e4 = *(const float4*)(be2 + t * HC + lane * 4);
    float y[4];
    y[0] = fmaxf((x[0] - mean) * rstd * g4.x + e4.x, 0.f);
    y[1] = fmaxf((x[1] - mean) * rstd * g4.y + e4.y, 0.f);
    y[2] = fmaxf((x[2] - mean) * rstd * g4.z + e4.z, 0.f);
    y[3] = fmaxf((x[3] - mean) * rstd * g4.w + e4.w, 0.f);
    float r0 = 0.f, r1 = 0.f, r2 = 0.f, r3 = 0.f;
    const float* w = Ww + (size_t)t * H2C * 4 + lane * 16;
    for (int i = 0; i < 4; ++i) {
        float4 wv = *(const float4*)(w + i * 4);
        r0 += y[i] * wv.x; r1 += y[i] * wv.y; r2 += y[i] * wv.z; r3 += y[i] * wv.w;
    }
    for (int o = 32; o > 0; o >>= 1) {
        r0 += __shfl_xor(r0, o); r1 += __shfl_xor(r1, o);
        r2 += __shfl_xor(r2, o); r3 += __shfl_xor(r3, o);
    }
    if (lane == 0) {
        r0 += tb[t * 4 + 0]; r1 += tb[t * 4 + 1]; r2 += tb[t * 4 + 2]; r3 += tb[t * 4 + 3];
        float mx = fmaxf(fmaxf(r0, r1), fmaxf(r2, r3));
        float q0 = expf(r0 - mx), q1 = expf(r1 - mx), q2 = expf(r2 - mx), q3 = expf(r3 - mx);
        float si = 1.f / (q0 + q1 + q2 + q3);
        int orig = order[p];
        *(float4*)(out + (size_t)orig * 4) = make_float4(q0 * si, q1 * si, q2 * si, q3 * si);
    }
}

extern "C" void kernel_launch(void* const* d_in, const int* in_sizes, int n_in,
                              void* d_out, int out_size, void* d_ws, size_t ws_size,
                              hipStream_t stream) {
    const float* f0 = (const float*)d_in[0];
    const float* f1 = (const float*)d_in[1];
    const float* f2 = (const float*)d_in[2];
    const float* f3 = (const float*)d_in[3];
    const float* W1 = (const float*)d_in[4];
    const float* b1 = (const float*)d_in[5];
    const float* g1 = (const float*)d_in[6];
    const float* be1 = (const float*)d_in[7];
    const float* W2 = (const float*)d_in[8];
    const float* b2 = (const float*)d_in[9];
    const float* g2 = (const float*)d_in[10];
    const float* be2 = (const float*)d_in[11];
    const float* temb = (const float*)d_in[12];
    const float* Ww = (const float*)d_in[13];
    const float* bw = (const float*)d_in[14];
    const int* task_ids = (const int*)d_in[15];
    float* out = (float*)d_out;

    char* ws = (char*)d_ws;
    size_t off = 0;
    auto walloc = [&](size_t bytes) -> void* {
        void* p = ws + off;
        off = (off + bytes + 255) & ~(size_t)255;
        return p;
    };
    int* counts = (int*)walloc(32);
    int* cursor = (int*)walloc(32);
    int* seg = (int*)walloc(32);
    float* tb = (float*)walloc(128);
    int* order = (int*)walloc((size_t)B_N * 4);
    int* tpos = (int*)walloc((size_t)B_N * 4);
    unsigned short* Xb = (unsigned short*)walloc((size_t)B_N * DIN * 2);
    unsigned short* W1t = (unsigned short*)walloc((size_t)T_N * H2C * DIN * 2);
    unsigned short* W2t = (unsigned short*)walloc((size_t)T_N * HC * H2C * 2);
    float* h1raw = (float*)walloc((size_t)B_N * H2C * 4);
    unsigned short* h1b = (unsigned short*)walloc((size_t)B_N * H2C * 2);
    float* h2raw = (float*)walloc((size_t)B_N * HC * 4);

    hipMemsetAsync(d_ws, 0, 256, stream);
    k_hist<<<16, 256, 0, stream>>>(task_ids, counts);
    k_scan<<<1, 64, 0, stream>>>(counts, seg, cursor);
    k_scatter<<<16, 256, 0, stream>>>(task_ids, cursor, order, tpos);
    k_convert_x<<<8192, 256, 0, stream>>>(f0, f1, f2, f3, Xb);
    k_transpose_bf<<<dim3(DIN / 32, H2C / 32, T_N), 256, 0, stream>>>(W1, W1t, DIN, H2C);
    k_transpose_bf<<<dim3(H2C / 32, HC / 32, T_N), 256, 0, stream>>>(W2, W2t, H2C, HC);
    k_taskbias<<<1, 64, 0, stream>>>(temb, Ww, bw, tb);
    k_gemm<<<T_N * 32 * 4, 256, 0, stream>>>(Xb, W1t, h1raw, order, seg, counts, DIN, 32, 4, H2C);
    k_ln1<<<B_N / 4, 256, 0, stream>>>(h1raw, b1, g1, be1, tpos, h1b);
    k_gemm<<<T_N * 32 * 2, 256, 0, stream>>>(h1b, W2t, h2raw, nullptr, seg, counts, H2C, 32, 2, HC);
    k_ln2_final<<<B_N / 4, 256, 0, stream>>>(h2raw, b2, g2, be2, Ww, tb, tpos, order, out);
}

// Round 2
// 145.311 us; speedup vs baseline: 2.9783x; 2.9783x over previous
//
#include <hip/hip_runtime.h>
#include <hip/hip_bf16.h>
#include <stdint.h>

#define B_N 4096
#define T_N 8
#define DIN 4096
#define H2C 512
#define HC 256

typedef __attribute__((ext_vector_type(8))) short bf16x8;
typedef __attribute__((ext_vector_type(4))) float f32x4;

static __device__ __forceinline__ unsigned short f2bf(float f) {
    union { float f; uint32_t u; } v; v.f = f;
    uint32_t u = v.u;
    uint32_t r = (u + 0x7FFFu + ((u >> 16) & 1u)) >> 16;
    return (unsigned short)r;
}

static __device__ __forceinline__ void gl2lds16(const unsigned short* g, unsigned short* l) {
    __builtin_amdgcn_global_load_lds(
        (const __attribute__((address_space(1))) unsigned int*)(g),
        (__attribute__((address_space(3))) unsigned int*)(l), 16, 0, 0);
}

// ---------------- fused prep: hist + scan + scatter + per-task bias ----------------
__global__ void k_prep(const int* __restrict__ task_ids,
                       const float* __restrict__ temb, const float* __restrict__ Ww,
                       const float* __restrict__ bw,
                       int* __restrict__ counts, int* __restrict__ seg,
                       int* __restrict__ order, int* __restrict__ tpos,
                       float* __restrict__ tb) {
    __shared__ int lc[T_N], lseg[T_N], lcur[T_N];
    int tid = threadIdx.x;                       // 512 threads
    if (tid < T_N) lc[tid] = 0;
    __syncthreads();
    int myt[8];
    for (int i = 0; i < 8; ++i) {
        myt[i] = task_ids[tid * 8 + i];
        atomicAdd(&lc[myt[i]], 1);
    }
    __syncthreads();
    if (tid == 0) {
        int s = 0;
        for (int t = 0; t < T_N; ++t) { lseg[t] = s; lcur[t] = s; s += lc[t]; }
    }
    __syncthreads();
    for (int i = 0; i < 8; ++i) {
        int p = atomicAdd(&lcur[myt[i]], 1);
        order[p] = tid * 8 + i;
        tpos[p] = myt[i];
    }
    if (tid < T_N) { counts[tid] = lc[tid]; seg[tid] = lseg[tid]; }
    // per-task bias: bw + task_emb @ Ww[256:512]  (wave t handles task t)
    int wv = tid >> 6, lane = tid & 63;
    int m = lane & 3, hb = (lane >> 2) * 16;
    float s = 0.f;
    const float* te = temb + wv * HC;
    const float* w = Ww + (size_t)wv * H2C * 4 + (size_t)(HC + hb) * 4 + m;
    for (int h = 0; h < 16; ++h) s += te[hb + h] * w[h * 4];
    for (int o = 4; o < 64; o <<= 1) s += __shfl_xor(s, o);
    if (lane < 4) tb[wv * 4 + lane] = s + bw[wv * 4 + lane];
}

// ---------------- X gather (sorted order) + concat + fp32->bf16 ----------------
__global__ void k_convert_x(const float* __restrict__ f0, const float* __restrict__ f1,
                            const float* __restrict__ f2, const float* __restrict__ f3,
                            const int* __restrict__ order, unsigned short* __restrict__ X) {
    int g = blockIdx.x * 256 + threadIdx.x;      // 2,097,152 granules of 8 elems
    int p = g >> 9;                              // sorted row
    int col = (g & 511) * 8;
    int m = col >> 10, d = col & 1023;
    int b = order[p];
    const float* s = (m == 0) ? f0 : (m == 1) ? f1 : (m == 2) ? f2 : f3;
    const float4* sp = (const float4*)(s + (size_t)b * 1024 + d);
    float4 a = sp[0], c = sp[1];
    uint4 w;
    w.x = (uint32_t)f2bf(a.x) | ((uint32_t)f2bf(a.y) << 16);
    w.y = (uint32_t)f2bf(a.z) | ((uint32_t)f2bf(a.w) << 16);
    w.z = (uint32_t)f2bf(c.x) | ((uint32_t)f2bf(c.y) << 16);
    w.w = (uint32_t)f2bf(c.z) | ((uint32_t)f2bf(c.w) << 16);
    *(uint4*)(X + (size_t)p * DIN + col) = w;
}

// ---------------- weight transpose [T][R][C] fp32 -> [T][C][R] bf16 ----------------
__global__ void k_transpose_bf(const float* __restrict__ in, unsigned short* __restrict__ out,
                               int R, int C) {
    __shared__ float tile[32][33];
    int t = blockIdx.z;
    const float* ip = in + (size_t)t * R * C;
    unsigned short* op = out + (size_t)t * R * C;
    int r0 = blockIdx.x * 32, c0 = blockIdx.y * 32;
    int c = threadIdx.x & 31, r = threadIdx.x >> 5;
    for (int i = 0; i < 4; ++i) {
        int rr = r + i * 8;
        tile[rr][c] = ip[(size_t)(r0 + rr) * C + c0 + c];
    }
    __syncthreads();
    for (int i = 0; i < 4; ++i) {
        int rr = r + i * 8;
        op[(size_t)(c0 + rr) * R + r0 + c] = f2bf(tile[c][rr]);
    }
}

// ---------------- grouped GEMM, m97-style: global_load_lds + 2-phase dbuf ----------------
// A sorted [B][K] bf16, Bt [T][N][K] bf16, C [B][N] fp32 (sorted rows)
__launch_bounds__(256)
__global__ void k_gemm(const unsigned short* __restrict__ A, const unsigned short* __restrict__ Bt,
                       float* __restrict__ C,
                       const int* __restrict__ seg, const int* __restrict__ counts,
                       int K, int rowtiles, int coltiles, int Ntot) {
    int t = blockIdx.x / (rowtiles * coltiles);
    int rem = blockIdx.x % (rowtiles * coltiles);
    int rt = rem / coltiles, ct = rem % coltiles;
    int cnt = counts[t];
    if (rt * 128 >= cnt) return;
    int seg0 = seg[t];

    extern __shared__ unsigned short lds[];      // [2][A:8192 | B:8192] = 64 KB

    int tid = threadIdx.x, lane = tid & 63, w = tid >> 6;
    int wm = w >> 1, wn = w & 1;

    // lane-fixed staging source pointers (contiguous rows, 8 rows per 1KB instr)
    const unsigned short* pA[4];
    const unsigned short* pB[4];
    const unsigned short* Bbase = Bt + (size_t)t * Ntot * K;
    for (int j = 0; j < 4; ++j) {
        int r = rt * 128 + w * 32 + j * 8 + (lane >> 3);
        if (r >= cnt) r = cnt - 1;
        pA[j] = A + (size_t)(seg0 + r) * K + (lane & 7) * 8;
        int rb = ct * 128 + w * 32 + j * 8 + (lane >> 3);
        pB[j] = Bbase + (size_t)rb * K + (lane & 7) * 8;
    }

    f32x4 acc[4][4];
    for (int m = 0; m < 4; ++m)
        for (int n = 0; n < 4; ++n)
            acc[m][n] = (f32x4){0.f, 0.f, 0.f, 0.f};

    auto stage = [&](int buf, int k0) {
        unsigned short* dA = lds + buf * 16384 + w * 2048;
        unsigned short* dB = dA + 8192;
        for (int j = 0; j < 4; ++j) gl2lds16(pA[j] + k0, dA + j * 512);
        for (int j = 0; j < 4; ++j) gl2lds16(pB[j] + k0, dB + j * 512);
    };

    int nit = K >> 6;
    stage(0, 0);
    __syncthreads();                             // drain prologue stage
    int cur = 0;
    for (int it = 0; it < nit; ++it) {
        if (it + 1 < nit) stage(cur ^ 1, (it + 1) * 64);   // async prefetch in flight
        const unsigned short* As = lds + cur * 16384;
        const unsigned short* Bs = As + 8192;
        for (int ks = 0; ks < 2; ++ks) {
            int colb = ks * 32 + (lane >> 4) * 8;
            bf16x8 af[4], bfv[4];
            for (int m = 0; m < 4; ++m) {
                int row = wm * 64 + m * 16 + (lane & 15);
                af[m] = *(const bf16x8*)&As[row * 64 + colb];
            }
            for (int n = 0; n < 4; ++n) {
                int row = wn * 64 + n * 16 + (lane & 15);
                bfv[n] = *(const bf16x8*)&Bs[row * 64 + colb];
            }
            for (int m = 0; m < 4; ++m)
                for (int n = 0; n < 4; ++n)
                    acc[m][n] = __builtin_amdgcn_mfma_f32_16x16x32_bf16(af[m], bfv[n], acc[m][n], 0, 0, 0);
        }
        __syncthreads();                         // drains prefetch vmcnt under compute shadow
        cur ^= 1;
    }

    for (int m = 0; m < 4; ++m) {
        for (int n = 0; n < 4; ++n) {
            int col = ct * 128 + wn * 64 + n * 16 + (lane & 15);
            for (int j = 0; j < 4; ++j) {
                int row = wm * 64 + m * 16 + (lane >> 4) * 4 + j;
                int pt = rt * 128 + row;
                if (pt < cnt)
                    C[(size_t)(seg0 + pt) * Ntot + col] = acc[m][n][j];
            }
        }
    }
}

// ---------------- LN1 + ReLU + bf16 (rows sorted) ----------------
__global__ void k_ln1(const float* __restrict__ h1raw, const float* __restrict__ b1,
                      const float* __restrict__ g1, const float* __restrict__ be1,
                      const int* __restrict__ tpos, unsigned short* __restrict__ h1b) {
    int p = blockIdx.x * 4 + (threadIdx.x >> 6);
    int lane = threadIdx.x & 63;
    int t = tpos[p];
    const float* r = h1raw + (size_t)p * H2C + lane * 8;
    const float* bb = b1 + t * H2C + lane * 8;
    float4 v0 = *(const float4*)r, v1 = *(const float4*)(r + 4);
    float4 q0 = *(const float4*)bb, q1 = *(const float4*)(bb + 4);
    float x[8] = {v0.x + q0.x, v0.y + q0.y, v0.z + q0.z, v0.w + q0.w,
                  v1.x + q1.x, v1.y + q1.y, v1.z + q1.z, v1.w + q1.w};
    float s = 0.f, sq = 0.f;
    for (int i = 0; i < 8; ++i) { s += x[i]; sq += x[i] * x[i]; }
    for (int o = 32; o > 0; o >>= 1) { s += __shfl_xor(s, o); sq += __shfl_xor(sq, o); }
    float mean = s * (1.0f / H2C);
    float var = sq * (1.0f / H2C) - mean * mean;
    float rstd = rsqrtf(var + 1e-5f);
    const float* gg = g1 + t * H2C + lane * 8;
    const float* ee = be1 + t * H2C + lane * 8;
    float4 g0 = *(const float4*)gg, g1v = *(const float4*)(gg + 4);
    float4 e0 = *(const float4*)ee, e1v = *(const float4*)(ee + 4);
    float gA[8] = {g0.x, g0.y, g0.z, g0.w, g1v.x, g1v.y, g1v.z, g1v.w};
    float eA[8] = {e0.x, e0.y, e0.z, e0.w, e1v.x, e1v.y, e1v.z, e1v.w};
    unsigned short y[8];
    for (int i = 0; i < 8; ++i)
        y[i] = f2bf(fmaxf((x[i] - mean) * rstd * gA[i] + eA[i], 0.f));
    uint4 w;
    w.x = (uint32_t)y[0] | ((uint32_t)y[1] << 16);
    w.y = (uint32_t)y[2] | ((uint32_t)y[3] << 16);
    w.z = (uint32_t)y[4] | ((uint32_t)y[5] << 16);
    w.w = (uint32_t)y[6] | ((uint32_t)y[7] << 16);
    *(uint4*)(h1b + (size_t)p * H2C + lane * 8) = w;
}

// ---------------- LN2 + ReLU + weight-net dot + softmax + scatter ----------------
__global__ void k_ln2_final(const float* __restrict__ h2raw, const float* __restrict__ b2,
                            const float* __restrict__ g2, const float* __restrict__ be2,
                            const float* __restrict__ Ww, const float* __restrict__ tb,
                            const int* __restrict__ tpos, const int* __restrict__ order,
                            float* __restrict__ out) {
    int p = blockIdx.x * 4 + (threadIdx.x >> 6);
    int lane = threadIdx.x & 63;
    int t = tpos[p];
    float4 x4 = *(const float4*)(h2raw + (size_t)p * HC + lane * 4);
    float4 b4 = *(const float4*)(b2 + t * HC + lane * 4);
    float x[4] = {x4.x + b4.x, x4.y + b4.y, x4.z + b4.z, x4.w + b4.w};
    float s = 0.f, sq = 0.f;
    for (int i = 0; i < 4; ++i) { s += x[i]; sq += x[i] * x[i]; }
    for (int o = 32; o > 0; o >>= 1) { s += __shfl_xor(s, o); sq += __shfl_xor(sq, o); }
    float mean = s * (1.0f / HC);
    float var = sq * (1.0f / HC) - mean * mean;
    float rstd = rsqrtf(var + 1e-5f);
    float4 g4 = *(const float4*)(g2 + t * HC + lane * 4);
    float4 e4 = *(const float4*)(be2 + t * HC + lane * 4);
    float y[4];
    y[0] = fmaxf((x[0] - mean) * rstd * g4.x + e4.x, 0.f);
    y[1] = fmaxf((x[1] - mean) * rstd * g4.y + e4.y, 0.f);
    y[2] = fmaxf((x[2] - mean) * rstd * g4.z + e4.z, 0.f);
    y[3] = fmaxf((x[3] - mean) * rstd * g4.w + e4.w, 0.f);
    float r0 = 0.f, r1 = 0.f, r2 = 0.f, r3 = 0.f;
    const float* w = Ww + (size_t)t * H2C * 4 + lane * 16;
    for (int i = 0; i < 4; ++i) {
        float4 wv = *(const float4*)(w + i * 4);
        r0 += y[i] * wv.x; r1 += y[i] * wv.y; r2 += y[i] * wv.z; r3 += y[i] * wv.w;
    }
    for (int o = 32; o > 0; o >>= 1) {
        r0 += __shfl_xor(r0, o); r1 += __shfl_xor(r1, o);
        r2 += __shfl_xor(r2, o); r3 += __shfl_xor(r3, o);
    }
    if (lane == 0) {
        r0 += tb[t * 4 + 0]; r1 += tb[t * 4 + 1]; r2 += tb[t * 4 + 2]; r3 += tb[t * 4 + 3];
        float mx = fmaxf(fmaxf(r0, r1), fmaxf(r2, r3));
        float q0 = expf(r0 - mx), q1 = expf(r1 - mx), q2 = expf(r2 - mx), q3 = expf(r3 - mx);
        float si = 1.f / (q0 + q1 + q2 + q3);
        int orig = order[p];
        *(float4*)(out + (size_t)orig * 4) = make_float4(q0 * si, q1 * si, q2 * si, q3 * si);
    }
}

extern "C" void kernel_launch(void* const* d_in, const int* in_sizes, int n_in,
                              void* d_out, int out_size, void* d_ws, size_t ws_size,
                              hipStream_t stream) {
    const float* f0 = (const float*)d_in[0];
    const float* f1 = (const float*)d_in[1];
    const float* f2 = (const float*)d_in[2];
    const float* f3 = (const float*)d_in[3];
    const float* W1 = (const float*)d_in[4];
    const float* b1 = (const float*)d_in[5];
    const float* g1 = (const float*)d_in[6];
    const float* be1 = (const float*)d_in[7];
    const float* W2 = (const float*)d_in[8];
    const float* b2 = (const float*)d_in[9];
    const float* g2 = (const float*)d_in[10];
    const float* be2 = (const float*)d_in[11];
    const float* temb = (const float*)d_in[12];
    const float* Ww = (const float*)d_in[13];
    const float* bw = (const float*)d_in[14];
    const int* task_ids = (const int*)d_in[15];
    float* out = (float*)d_out;

    char* ws = (char*)d_ws;
    size_t off = 0;
    auto walloc = [&](size_t bytes) -> void* {
        void* p = ws + off;
        off = (off + bytes + 255) & ~(size_t)255;
        return p;
    };
    int* counts = (int*)walloc(32);
    int* seg = (int*)walloc(32);
    float* tb = (float*)walloc(128);
    int* order = (int*)walloc((size_t)B_N * 4);
    int* tpos = (int*)walloc((size_t)B_N * 4);
    unsigned short* Xb = (unsigned short*)walloc((size_t)B_N * DIN * 2);
    unsigned short* W1t = (unsigned short*)walloc((size_t)T_N * H2C * DIN * 2);
    unsigned short* W2t = (unsigned short*)walloc((size_t)T_N * HC * H2C * 2);
    float* h1raw = (float*)walloc((size_t)B_N * H2C * 4);
    unsigned short* h1b = (unsigned short*)walloc((size_t)B_N * H2C * 2);
    float* h2raw = (float*)walloc((size_t)B_N * HC * 4);

    k_prep<<<1, 512, 0, stream>>>(task_ids, temb, Ww, bw, counts, seg, order, tpos, tb);
    k_convert_x<<<8192, 256, 0, stream>>>(f0, f1, f2, f3, order, Xb);
    k_transpose_bf<<<dim3(DIN / 32, H2C / 32, T_N), 256, 0, stream>>>(W1, W1t, DIN, H2C);
    k_transpose_bf<<<dim3(H2C / 32, HC / 32, T_N), 256, 0, stream>>>(W2, W2t, H2C, HC);
    k_gemm<<<T_N * 32 * 4, 256, 65536, stream>>>(Xb, W1t, h1raw, seg, counts, DIN, 32, 4, H2C);
    k_ln1<<<B_N / 4, 256, 0, stream>>>(h1raw, b1, g1, be1, tpos, h1b);
    k_gemm<<<T_N * 32 * 2, 256, 65536, stream>>>(h1b, W2t, h2raw, seg, counts, H2C, 32, 2, HC);
    k_ln2_final<<<B_N / 4, 256, 0, stream>>>(h2raw, b2, g2, be2, Ww, tb, tpos, order, out);
}

// Round 3
// 96.102 us; speedup vs baseline: 4.5034x; 1.5120x over previous
//
#include <hip/hip_runtime.h>
#include <hip/hip_bf16.h>
#include <stdint.h>

#define B_N 4096
#define T_N 8
#define DIN 4096
#define H2C 512
#define HC 256
#define MAXTILE 40

typedef __attribute__((ext_vector_type(8))) short bf16x8;
typedef __attribute__((ext_vector_type(4))) float f32x4;

static __device__ __forceinline__ unsigned short f2bf(float f) {
    union { float f; uint32_t u; } v; v.f = f;
    uint32_t u = v.u;
    uint32_t r = (u + 0x7FFFu + ((u >> 16) & 1u)) >> 16;
    return (unsigned short)r;
}

static __device__ __forceinline__ void gl2lds16(const unsigned short* g, unsigned short* l) {
    __builtin_amdgcn_global_load_lds(
        (const __attribute__((address_space(1))) unsigned int*)(g),
        (__attribute__((address_space(3))) unsigned int*)(l), 16, 0, 0);
}

static __device__ __forceinline__ int xcd_remap(int bid, int nwg) {
    int xcd = bid & 7, idx = bid >> 3;
    int q = nwg >> 3, r = nwg & 7;
    return (xcd < r ? xcd * (q + 1) : r * (q + 1) + (xcd - r) * q) + idx;
}

// ---------------- fused prep: hist + scan + scatter + tile table + per-task bias ----------------
__global__ void k_prep(const int* __restrict__ task_ids,
                       const float* __restrict__ temb, const float* __restrict__ Ww,
                       const float* __restrict__ bw,
                       int* __restrict__ counts, int* __restrict__ seg,
                       int* __restrict__ order, int* __restrict__ tpos,
                       int* __restrict__ tiles, int* __restrict__ ntile,
                       float* __restrict__ tb) {
    __shared__ int lc[T_N], lseg[T_N], lcur[T_N];
    int tid = threadIdx.x;                       // 512 threads
    if (tid < T_N) lc[tid] = 0;
    __syncthreads();
    int myt[8];
    for (int i = 0; i < 8; ++i) {
        myt[i] = task_ids[tid * 8 + i];
        atomicAdd(&lc[myt[i]], 1);
    }
    __syncthreads();
    if (tid == 0) {
        int s = 0;
        for (int t = 0; t < T_N; ++t) { lseg[t] = s; lcur[t] = s; s += lc[t]; }
        int n = 0;
        for (int t = 0; t < T_N; ++t)
            for (int r0 = 0; r0 < lc[t]; r0 += 128) {
                tiles[2 * n] = t; tiles[2 * n + 1] = r0; ++n;
            }
        ntile[0] = n;
    }
    __syncthreads();
    for (int i = 0; i < 8; ++i) {
        int p = atomicAdd(&lcur[myt[i]], 1);
        order[p] = tid * 8 + i;
        tpos[p] = myt[i];
    }
    if (tid < T_N) { counts[tid] = lc[tid]; seg[tid] = lseg[tid]; }
    // per-task bias: bw + task_emb @ Ww[256:512]  (wave t handles task t)
    int wv = tid >> 6, lane = tid & 63;
    int m = lane & 3, hb = (lane >> 2) * 16;
    float s = 0.f;
    const float* te = temb + wv * HC;
    const float* w = Ww + (size_t)wv * H2C * 4 + (size_t)(HC + hb) * 4 + m;
    for (int h = 0; h < 16; ++h) s += te[hb + h] * w[h * 4];
    for (int o = 4; o < 64; o <<= 1) s += __shfl_xor(s, o);
    if (lane < 4) tb[wv * 4 + lane] = s + bw[wv * 4 + lane];
}

// ---------------- X gather (sorted order) + concat + fp32->bf16 ----------------
__global__ void k_convert_x(const float* __restrict__ f0, const float* __restrict__ f1,
                            const float* __restrict__ f2, const float* __restrict__ f3,
                            const int* __restrict__ order, unsigned short* __restrict__ X) {
    int g = blockIdx.x * 256 + threadIdx.x;
    int p = g >> 9;                              // sorted row
    int col = (g & 511) * 8;
    int m = col >> 10, d = col & 1023;
    int b = order[p];
    const float* s = (m == 0) ? f0 : (m == 1) ? f1 : (m == 2) ? f2 : f3;
    const float4* sp = (const float4*)(s + (size_t)b * 1024 + d);
    float4 a = sp[0], c = sp[1];
    uint4 w;
    w.x = (uint32_t)f2bf(a.x) | ((uint32_t)f2bf(a.y) << 16);
    w.y = (uint32_t)f2bf(a.z) | ((uint32_t)f2bf(a.w) << 16);
    w.z = (uint32_t)f2bf(c.x) | ((uint32_t)f2bf(c.y) << 16);
    w.w = (uint32_t)f2bf(c.z) | ((uint32_t)f2bf(c.w) << 16);
    *(uint4*)(X + (size_t)p * DIN + col) = w;
}

// ---------------- weight transpose [T][R][C] fp32 -> [T][C][R] bf16, 64x64 tiles ----------------
__global__ void k_transpose_bf(const float* __restrict__ in, unsigned short* __restrict__ out,
                               int R, int C) {
    __shared__ float tile[64][65];
    int t = blockIdx.z;
    const float* ip = in + (size_t)t * R * C;
    unsigned short* op = out + (size_t)t * R * C;
    int r0 = blockIdx.x * 64, c0 = blockIdx.y * 64;
    int tid = threadIdx.x;
    int lr = tid >> 4, lc4 = (tid & 15) * 4;
    for (int i = 0; i < 4; ++i) {
        float4 v = *(const float4*)&ip[(size_t)(r0 + lr + i * 16) * C + c0 + lc4];
        tile[lr + i * 16][lc4 + 0] = v.x;
        tile[lr + i * 16][lc4 + 1] = v.y;
        tile[lr + i * 16][lc4 + 2] = v.z;
        tile[lr + i * 16][lc4 + 3] = v.w;
    }
    __syncthreads();
    int r4 = (tid & 15) * 4;
    for (int i = 0; i < 4; ++i) {
        int cc = i * 16 + (tid >> 4);
        uint2 wv;
        wv.x = (uint32_t)f2bf(tile[r4 + 0][cc]) | ((uint32_t)f2bf(tile[r4 + 1][cc]) << 16);
        wv.y = (uint32_t)f2bf(tile[r4 + 2][cc]) | ((uint32_t)f2bf(tile[r4 + 3][cc]) << 16);
        *(uint2*)&op[(size_t)(c0 + cc) * R + r0 + r4] = wv;
    }
}

// ---------------- grouped GEMM: tile table, split-K, swizzled LDS, global_load_lds ----------------
// A sorted [B][K] bf16, Bt [T][NT][K] bf16, C [SPLITK][B][NT] fp32 (sorted rows)
template<int BM, int BN, int WR, int WC, int COLT, int SPLITK>
__launch_bounds__(256)
__global__ void k_gemm(const unsigned short* __restrict__ A, const unsigned short* __restrict__ Bt,
                       float* __restrict__ C,
                       const int* __restrict__ seg, const int* __restrict__ counts,
                       const int* __restrict__ tiles, const int* __restrict__ ntile,
                       int K, int nwg) {
    constexpr int NT = COLT * BN;
    constexpr int GA = BM / 32, GB = BN / 32;
    constexpr int MR = BM / WR / 16, NR = BN / WC / 16;
    constexpr int BUFSZ = (BM + BN) * 64;        // shorts per buffer

    int id = xcd_remap(blockIdx.x, nwg);
    int kc = id % SPLITK;
    int rest = id / SPLITK;
    int ct = rest % COLT, tix = rest / COLT;
    if (tix >= ntile[0]) return;
    int t = tiles[2 * tix], row0 = tiles[2 * tix + 1];
    int cnt = counts[t];
    int rows = cnt - row0; if (rows > BM) rows = BM;
    int seg0 = seg[t];
    int Kc = K / SPLITK;
    int kb = kc * Kc;

    extern __shared__ unsigned short lds[];

    int tid = threadIdx.x, lane = tid & 63, w = tid >> 6;
    int wm = w / WC, wn = w % WC;

    // staging source pointers: pre-swizzled global granule (involution with read side)
    const unsigned short* pA[GA];
    const unsigned short* pB[GB];
    #pragma unroll
    for (int j = 0; j < GA; ++j) {
        int row = j * 32 + (tid >> 3);
        int rl = row < rows ? row : rows - 1;
        int colg = (tid & 7) ^ (row & 7);
        pA[j] = A + (size_t)(seg0 + row0 + rl) * K + kb + colg * 8;
    }
    #pragma unroll
    for (int j = 0; j < GB; ++j) {
        int row = j * 32 + (tid >> 3);
        int colg = (tid & 7) ^ (row & 7);
        pB[j] = Bt + ((size_t)t * NT + ct * BN + row) * K + kb + colg * 8;
    }

    f32x4 acc[MR][NR];
    #pragma unroll
    for (int m = 0; m < MR; ++m)
        #pragma unroll
        for (int n = 0; n < NR; ++n)
            acc[m][n] = (f32x4){0.f, 0.f, 0.f, 0.f};

    auto stage = [&](int buf, int k0) {
        unsigned short* dA = lds + buf * BUFSZ + w * 512;
        unsigned short* dB = dA + BM * 64;
        #pragma unroll
        for (int j = 0; j < GA; ++j) gl2lds16(pA[j] + k0, dA + j * 2048);
        #pragma unroll
        for (int j = 0; j < GB; ++j) gl2lds16(pB[j] + k0, dB + j * 2048);
    };

    int nit = Kc >> 6;
    stage(0, 0);
    __syncthreads();
    int cur = 0;
    for (int it = 0; it < nit; ++it) {
        if (it + 1 < nit) stage(cur ^ 1, (it + 1) * 64);
        const unsigned short* As = lds + cur * BUFSZ;
        const unsigned short* Bs = As + BM * 64;
        #pragma unroll
        for (int ks = 0; ks < 2; ++ks) {
            int g = ks * 4 + (lane >> 4);
            bf16x8 af[MR], bfv[NR];
            #pragma unroll
            for (int m = 0; m < MR; ++m) {
                int row = wm * (BM / WR) + m * 16 + (lane & 15);
                af[m] = *(const bf16x8*)&As[row * 64 + (g ^ (row & 7)) * 8];
            }
            #pragma unroll
            for (int n = 0; n < NR; ++n) {
                int row = wn * (BN / WC) + n * 16 + (lane & 15);
                bfv[n] = *(const bf16x8*)&Bs[row * 64 + (g ^ (row & 7)) * 8];
            }
            #pragma unroll
            for (int m = 0; m < MR; ++m)
                #pragma unroll
                for (int n = 0; n < NR; ++n)
                    acc[m][n] = __builtin_amdgcn_mfma_f32_16x16x32_bf16(af[m], bfv[n], acc[m][n], 0, 0, 0);
        }
        __syncthreads();
        cur ^= 1;
    }

    float* Cb = C + (size_t)kc * B_N * NT;
    #pragma unroll
    for (int m = 0; m < MR; ++m) {
        #pragma unroll
        for (int n = 0; n < NR; ++n) {
            int col = ct * BN + wn * (BN / WC) + n * 16 + (lane & 15);
            #pragma unroll
            for (int j = 0; j < 4; ++j) {
                int rl = wm * (BM / WR) + m * 16 + (lane >> 4) * 4 + j;
                if (rl < rows)
                    Cb[(size_t)(seg0 + row0 + rl) * NT + col] = acc[m][n][j];
            }
        }
    }
}

// ---------------- LN1 + ReLU + bf16 (rows sorted), sums split-K partials ----------------
__global__ void k_ln1(const float* __restrict__ h1p, const float* __restrict__ b1,
                      const float* __restrict__ g1, const float* __restrict__ be1,
                      const int* __restrict__ tpos, unsigned short* __restrict__ h1b) {
    int p = blockIdx.x * 4 + (threadIdx.x >> 6);
    int lane = threadIdx.x & 63;
    int t = tpos[p];
    const float* r0p = h1p + (size_t)p * H2C + lane * 8;
    const float* r1p = r0p + (size_t)B_N * H2C;
    const float* bb = b1 + t * H2C + lane * 8;
    float4 v0 = *(const float4*)r0p, v1 = *(const float4*)(r0p + 4);
    float4 u0 = *(const float4*)r1p, u1 = *(const float4*)(r1p + 4);
    float4 q0 = *(const float4*)bb, q1 = *(const float4*)(bb + 4);
    float x[8] = {v0.x + u0.x + q0.x, v0.y + u0.y + q0.y, v0.z + u0.z + q0.z, v0.w + u0.w + q0.w,
                  v1.x + u1.x + q1.x, v1.y + u1.y + q1.y, v1.z + u1.z + q1.z, v1.w + u1.w + q1.w};
    float s = 0.f, sq = 0.f;
    for (int i = 0; i < 8; ++i) { s += x[i]; sq += x[i] * x[i]; }
    for (int o = 32; o > 0; o >>= 1) { s += __shfl_xor(s, o); sq += __shfl_xor(sq, o); }
    float mean = s * (1.0f / H2C);
    float var = sq * (1.0f / H2C) - mean * mean;
    float rstd = rsqrtf(var + 1e-5f);
    const float* gg = g1 + t * H2C + lane * 8;
    const float* ee = be1 + t * H2C + lane * 8;
    float4 g0 = *(const float4*)gg, g1v = *(const float4*)(gg + 4);
    float4 e0 = *(const float4*)ee, e1v = *(const float4*)(ee + 4);
    float gA[8] = {g0.x, g0.y, g0.z, g0.w, g1v.x, g1v.y, g1v.z, g1v.w};
    float eA[8] = {e0.x, e0.y, e0.z, e0.w, e1v.x, e1v.y, e1v.z, e1v.w};
    unsigned short y[8];
    for (int i = 0; i < 8; ++i)
        y[i] = f2bf(fmaxf((x[i] - mean) * rstd * gA[i] + eA[i], 0.f));
    uint4 w;
    w.x = (uint32_t)y[0] | ((uint32_t)y[1] << 16);
    w.y = (uint32_t)y[2] | ((uint32_t)y[3] << 16);
    w.z = (uint32_t)y[4] | ((uint32_t)y[5] << 16);
    w.w = (uint32_t)y[6] | ((uint32_t)y[7] << 16);
    *(uint4*)(h1b + (size_t)p * H2C + lane * 8) = w;
}

// ---------------- LN2 + ReLU + weight-net dot + softmax + scatter ----------------
__global__ void k_ln2_final(const float* __restrict__ h2p, const float* __restrict__ b2,
                            const float* __restrict__ g2, const float* __restrict__ be2,
                            const float* __restrict__ Ww, const float* __restrict__ tb,
                            const int* __restrict__ tpos, const int* __restrict__ order,
                            float* __restrict__ out) {
    int p = blockIdx.x * 4 + (threadIdx.x >> 6);
    int lane = threadIdx.x & 63;
    int t = tpos[p];
    float4 x4 = *(const float4*)(h2p + (size_t)p * HC + lane * 4);
    float4 z4 = *(const float4*)(h2p + (size_t)B_N * HC + (size_t)p * HC + lane * 4);
    float4 b4 = *(const float4*)(b2 + t * HC + lane * 4);
    float x[4] = {x4.x + z4.x + b4.x, x4.y + z4.y + b4.y, x4.z + z4.z + b4.z, x4.w + z4.w + b4.w};
    float s = 0.f, sq = 0.f;
    for (int i = 0; i < 4; ++i) { s += x[i]; sq += x[i] * x[i]; }
    for (int o = 32; o > 0; o >>= 1) { s += __shfl_xor(s, o); sq += __shfl_xor(sq, o); }
    float mean = s * (1.0f / HC);
    float var = sq * (1.0f / HC) - mean * mean;
    float rstd = rsqrtf(var + 1e-5f);
    float4 g4 = *(const float4*)(g2 + t * HC + lane * 4);
    float4 e4 = *(const float4*)(be2 + t * HC + lane * 4);
    float y[4];
    y[0] = fmaxf((x[0] - mean) * rstd * g4.x + e4.x, 0.f);
    y[1] = fmaxf((x[1] - mean) * rstd * g4.y + e4.y, 0.f);
    y[2] = fmaxf((x[2] - mean) * rstd * g4.z + e4.z, 0.f);
    y[3] = fmaxf((x[3] - mean) * rstd * g4.w + e4.w, 0.f);
    float r0 = 0.f, r1 = 0.f, r2 = 0.f, r3 = 0.f;
    const float* w = Ww + (size_t)t * H2C * 4 + lane * 16;
    for (int i = 0; i < 4; ++i) {
        float4 wv = *(const float4*)(w + i * 4);
        r0 += y[i] * wv.x; r1 += y[i] * wv.y; r2 += y[i] * wv.z; r3 += y[i] * wv.w;
    }
    for (int o = 32; o > 0; o >>= 1) {
        r0 += __shfl_xor(r0, o); r1 += __shfl_xor(r1, o);
        r2 += __shfl_xor(r2, o); r3 += __shfl_xor(r3, o);
    }
    if (lane == 0) {
        r0 += tb[t * 4 + 0]; r1 += tb[t * 4 + 1]; r2 += tb[t * 4 + 2]; r3 += tb[t * 4 + 3];
        float mx = fmaxf(fmaxf(r0, r1), fmaxf(r2, r3));
        float q0 = expf(r0 - mx), q1 = expf(r1 - mx), q2 = expf(r2 - mx), q3 = expf(r3 - mx);
        float si = 1.f / (q0 + q1 + q2 + q3);
        int orig = order[p];
        *(float4*)(out + (size_t)orig * 4) = make_float4(q0 * si, q1 * si, q2 * si, q3 * si);
    }
}

extern "C" void kernel_launch(void* const* d_in, const int* in_sizes, int n_in,
                              void* d_out, int out_size, void* d_ws, size_t ws_size,
                              hipStream_t stream) {
    const float* f0 = (const float*)d_in[0];
    const float* f1 = (const float*)d_in[1];
    const float* f2 = (const float*)d_in[2];
    const float* f3 = (const float*)d_in[3];
    const float* W1 = (const float*)d_in[4];
    const float* b1 = (const float*)d_in[5];
    const float* g1 = (const float*)d_in[6];
    const float* be1 = (const float*)d_in[7];
    const float* W2 = (const float*)d_in[8];
    const float* b2 = (const float*)d_in[9];
    const float* g2 = (const float*)d_in[10];
    const float* be2 = (const float*)d_in[11];
    const float* temb = (const float*)d_in[12];
    const float* Ww = (const float*)d_in[13];
    const float* bw = (const float*)d_in[14];
    const int* task_ids = (const int*)d_in[15];
    float* out = (float*)d_out;

    char* ws = (char*)d_ws;
    size_t off = 0;
    auto walloc = [&](size_t bytes) -> void* {
        void* p = ws + off;
        off = (off + bytes + 255) & ~(size_t)255;
        return p;
    };
    int* counts = (int*)walloc(32);
    int* seg = (int*)walloc(32);
    float* tb = (float*)walloc(128);
    int* tiles = (int*)walloc(MAXTILE * 2 * 4);
    int* ntile = (int*)walloc(4);
    int* order = (int*)walloc((size_t)B_N * 4);
    int* tpos = (int*)walloc((size_t)B_N * 4);
    unsigned short* Xb = (unsigned short*)walloc((size_t)B_N * DIN * 2);
    unsigned short* W1t = (unsigned short*)walloc((size_t)T_N * H2C * DIN * 2);
    unsigned short* W2t = (unsigned short*)walloc((size_t)T_N * HC * H2C * 2);
    float* h1p = (float*)walloc((size_t)2 * B_N * H2C * 4);
    unsigned short* h1b = (unsigned short*)walloc((size_t)B_N * H2C * 2);
    float* h2p = (float*)walloc((size_t)2 * B_N * HC * 4);

    k_prep<<<1, 512, 0, stream>>>(task_ids, temb, Ww, bw, counts, seg, order, tpos, tiles, ntile, tb);
    k_convert_x<<<8192, 256, 0, stream>>>(f0, f1, f2, f3, order, Xb);
    k_transpose_bf<<<dim3(DIN / 64, H2C / 64, T_N), 256, 0, stream>>>(W1, W1t, DIN, H2C);
    k_transpose_bf<<<dim3(H2C / 64, HC / 64, T_N), 256, 0, stream>>>(W2, W2t, H2C, HC);
    // gemm1: 128x128 tiles, 2x2 waves, COLT=4 (NT=512), split-K=2 -> 40*4*2=320 blocks
    k_gemm<128, 128, 2, 2, 4, 2><<<320, 256, 65536, stream>>>(Xb, W1t, h1p, seg, counts, tiles, ntile, DIN, 320);
    k_ln1<<<B_N / 4, 256, 0, stream>>>(h1p, b1, g1, be1, tpos, h1b);
    // gemm2: 128x64 tiles, 4x1 waves, COLT=4 (NT=256), split-K=2 -> 40*4*2=320 blocks
    k_gemm<128, 64, 4, 1, 4, 2><<<320, 256, 49152, stream>>>(h1b, W2t, h2p, seg, counts, tiles, ntile, H2C, 320);
    k_ln2_final<<<B_N / 4, 256, 0, stream>>>(h2p, b2, g2, be2, Ww, tb, tpos, order, out);
}